// Round 8
// baseline (481.129 us; speedup 1.0000x reference)
//
#include <hip/hip_runtime.h>
#include <hip/hip_bf16.h>

#define NN    2048
#define TIN   1000
#define NEDGE 32768
#define EMBD  768
#define FLATD 7680
#define BNEPS 1e-5f

typedef __attribute__((ext_vector_type(8))) short v8s;
typedef __attribute__((ext_vector_type(4))) float v4f;

__device__ inline unsigned short f2bf(float f) {
    unsigned u = __float_as_uint(f);
    u += 0x7fff + ((u >> 16) & 1);
    return (unsigned short)(u >> 16);
}
__device__ inline float bf2f(unsigned short h) {
    return __uint_as_float(((unsigned)h) << 16);
}
__device__ inline unsigned pack_bf2(float a, float b) {
    __hip_bfloat162 pk = __float22bfloat162_rn(make_float2(a, b));
    return *(unsigned*)&pk;
}

// ---------------------------------------------------------------- mega-prep: w2/w3 cvt, gw1/gw2 transpose, cnt zero, pos-MLP, x-moments
__global__ __launch_bounds__(256) void k_prep(
    const float* __restrict__ w2, unsigned short* __restrict__ w2bf,
    const float* __restrict__ w3, unsigned short* __restrict__ w3bf,
    const float* __restrict__ gw1, unsigned short* __restrict__ gw1T,
    const float* __restrict__ gw2, unsigned short* __restrict__ gw2T,
    int* __restrict__ cntz,
    const float* __restrict__ pos, const float* __restrict__ pw1, const float* __restrict__ pb1,
    const float* __restrict__ pw2, const float* __restrict__ pb2, float* __restrict__ pe,
    const float* __restrict__ x, float* __restrict__ part1)
{
    __shared__ float smem[4 * 1008 + 64];
    const int b = blockIdx.x, tid = threadIdx.x;
    if (b < 56) {
        int idx = b * 256 + tid;            // 14336 = 7*64*32
        int c1 = idx & 31, c2 = (idx >> 5) & 63, k = idx >> 11;
        w2bf[idx] = f2bf(w2[(c2 * 32 + c1) * 7 + k]);
    } else if (b < 280) {
        int idx = (b - 56) * 256 + tid;     // 57344
        int c1l = idx & 31, c2 = (idx >> 5) & 127, t = idx >> 12;
        int k = t % 7, ch = t / 7;
        w3bf[idx] = f2bf(w3[(c2 * 64 + ch * 32 + c1l) * 7 + k]);
    } else if (b < 1864) {
        // fp32 [R][C] -> bf16 [C][R], 64x64 tiles
        const float* src; unsigned short* dst; int R, Cc, t;
        if (b < 1720) { src = gw1; dst = gw1T; R = FLATD; Cc = EMBD; t = b - 280; }
        else          { src = gw2; dst = gw2T; R = EMBD;  Cc = EMBD; t = b - 1720; }
        const int r0 = (t / 12) * 64, c0 = (t % 12) * 64;
        unsigned short* tile = (unsigned short*)smem;   // [64][66]
        #pragma unroll
        for (int i = 0; i < 16; ++i) {
            int idx = i * 256 + tid;
            int r = idx >> 6, c = idx & 63;
            tile[r * 66 + c] = f2bf(src[(long)(r0 + r) * Cc + c0 + c]);
        }
        __syncthreads();
        #pragma unroll
        for (int i = 0; i < 16; ++i) {
            int idx = i * 256 + tid;
            int c = idx >> 6, r = idx & 63;
            dst[(long)(c0 + c) * R + r0 + r] = tile[r * 66 + c];
        }
    } else if (b < 1880) {
        cntz[(b - 1864) * 256 + tid] = 0;   // cnt + cursor (4096 ints)
    } else if (b < 2136) {
        // positional MLP: 8 n per block, 128 active threads
        float* hid = smem;
        const int t = b - 1880;
        float w10 = 0.f, w11 = 0.f, w12 = 0.f, b1j = 0.f, b2j = 0.f;
        if (tid < 128) {
            w10 = pw1[tid]; w11 = pw1[128 + tid]; w12 = pw1[256 + tid];
            b1j = pb1[tid]; b2j = pb2[tid];
        }
        for (int nl = 0; nl < 8; ++nl) {
            const int n = t * 8 + nl;
            float h = 0.f;
            if (tid < 128) {
                float p0 = pos[n * 3], p1 = pos[n * 3 + 1], p2 = pos[n * 3 + 2];
                h = fmaxf(fmaf(p0, w10, fmaf(p1, w11, fmaf(p2, w12, b1j))), 0.f);
            }
            __syncthreads();
            if (tid < 128) hid[tid] = h;
            __syncthreads();
            if (tid < 128) {
                float a = b2j;
                #pragma unroll 8
                for (int i = 0; i < 128; ++i) a = fmaf(hid[i], pw2[i * 128 + tid], a);
                pe[n * 128 + tid] = a;
            }
        }
    } else {
        // x moments for analytic BN1 (512 blocks)
        float* xs = smem;
        float* red = &smem[4032];
        const int n0 = (b - 2136) * 4;
        for (int idx = tid; idx < 4 * 1008; idx += 256) {
            int r = idx / 1008, p = idx % 1008;
            int t = p - 3;
            xs[idx] = (t >= 0 && t < TIN) ? x[(n0 + r) * TIN + t] : 0.f;
        }
        if (tid < 35) red[tid] = 0.f;
        __syncthreads();
        float S[7], C[28];
        #pragma unroll
        for (int i = 0; i < 7; ++i) S[i] = 0.f;
        #pragma unroll
        for (int i = 0; i < 28; ++i) C[i] = 0.f;
        for (int r = 0; r < 4; ++r) {
            #pragma unroll
            for (int i2 = 0; i2 < 4; ++i2) {
                const int t = tid + 256 * i2;
                if (t < TIN) {
                    float v[7];
                    #pragma unroll
                    for (int k = 0; k < 7; ++k) v[k] = xs[r * 1008 + t + k];
                    int p = 0;
                    #pragma unroll
                    for (int i = 0; i < 7; ++i) {
                        S[i] += v[i];
                        #pragma unroll
                        for (int j = i; j < 7; ++j) { C[p] = fmaf(v[i], v[j], C[p]); ++p; }
                    }
                }
            }
        }
        #pragma unroll
        for (int vv = 0; vv < 7; ++vv) {
            float s = S[vv];
            #pragma unroll
            for (int off = 32; off > 0; off >>= 1) s += __shfl_xor(s, off, 64);
            if ((tid & 63) == 0) atomicAdd(&red[vv], s);
        }
        #pragma unroll
        for (int vv = 0; vv < 28; ++vv) {
            float s = C[vv];
            #pragma unroll
            for (int off = 32; off > 0; off >>= 1) s += __shfl_xor(s, off, 64);
            if ((tid & 63) == 0) atomicAdd(&red[7 + vv], s);
        }
        __syncthreads();
        if (tid < 35) part1[tid * 512 + (b - 2136)] = red[tid];
    }
}

// ---------------------------------------------------------------- aux: block 0 = BN1 finalize (exact quadratic form); blocks 1..128 = CSR count
__global__ __launch_bounds__(256) void k_aux(
    const float* __restrict__ part, const float* __restrict__ w1, const float* __restrict__ b1,
    const float* __restrict__ g, const float* __restrict__ bt,
    float* __restrict__ scale, float* __restrict__ shift,
    const int* __restrict__ ei, int* __restrict__ cnt)
{
    const int tid = threadIdx.x;
    if (blockIdx.x != 0) {
        int e = (blockIdx.x - 1) * 256 + tid;
        if (e < NEDGE) atomicAdd(&cnt[ei[NEDGE + e]], 1);
        return;
    }
    __shared__ double SMp[140];
    __shared__ double SM[35];
    if (tid < 140) {
        int v = tid >> 2, l = tid & 3;
        double s = 0.0;
        for (int b = l; b < 512; b += 4) s += (double)part[v * 512 + b];
        SMp[tid] = s;
    }
    __syncthreads();
    if (tid < 35) SM[tid] = SMp[tid * 4] + SMp[tid * 4 + 1] + SMp[tid * 4 + 2] + SMp[tid * 4 + 3];
    __syncthreads();
    if (tid < 32) {
        double wv[7];
        #pragma unroll
        for (int k = 0; k < 7; ++k) wv[k] = (double)w1[tid * 7 + k];
        double m1 = 0.0;
        #pragma unroll
        for (int k = 0; k < 7; ++k) m1 += wv[k] * SM[k];
        double e2 = 0.0;
        int p = 7;
        #pragma unroll
        for (int i = 0; i < 7; ++i)
            #pragma unroll
            for (int j = i; j < 7; ++j) {
                double t = wv[i] * wv[j] * SM[p++];
                e2 += (i == j) ? t : 2.0 * t;
            }
        const double invN = 1.0 / 2048000.0;
        double bc = (double)b1[tid];
        double mean = m1 * invN + bc;
        double E2 = e2 * invN + 2.0 * bc * m1 * invN + bc * bc;
        double var = E2 - mean * mean;
        float rs = rsqrtf((float)var + BNEPS);
        float sc = g[tid] * rs;
        scale[tid] = sc;
        shift[tid] = bt[tid] - (float)mean * sc;
    }
}

// ---------------------------------------------------------------- stats reduce + bn finalize (layers 2,3)
__global__ __launch_bounds__(256) void k_reduce_stats(
    const float* __restrict__ part, const float* __restrict__ g, const float* __restrict__ bt,
    float* __restrict__ scale, float* __restrict__ shift,
    int count, int stride, int sqdelta, float inv_count)
{
    __shared__ double ss[4], qq[4];
    const int c = blockIdx.x, tid = threadIdx.x;
    double s = 0.0, q = 0.0;
    for (int i = tid; i < count; i += 256) {
        s += (double)part[c + (long)i * stride];
        q += (double)part[c + sqdelta + (long)i * stride];
    }
    #pragma unroll
    for (int off = 32; off > 0; off >>= 1) {
        s += __shfl_down(s, off, 64);
        q += __shfl_down(q, off, 64);
    }
    if ((tid & 63) == 0) { ss[tid >> 6] = s; qq[tid >> 6] = q; }
    __syncthreads();
    if (tid == 0) {
        double S = ss[0] + ss[1] + ss[2] + ss[3];
        double Q = qq[0] + qq[1] + qq[2] + qq[3];
        float mm = (float)(S * (double)inv_count);
        float vv = (float)(Q * (double)inv_count) - mm * mm;
        float rs = rsqrtf(vv + BNEPS);
        float sc = g[c] * rs;
        scale[c] = sc;
        shift[c] = bt[c] - mm * sc;
    }
}

// ---------------------------------------------------------------- conv2 MFMA: block per n, 4 chunks of 256t, wave tile 64t x 64c2
// LDS rows are 4 x 16B blocks; block b of row r stored at b^(r&3) (XOR swizzle: 8-way -> 4-way read conflicts)
__global__ __launch_bounds__(256, 3) void k_conv2(
    const float* __restrict__ x, const float* __restrict__ w1, const float* __restrict__ b1,
    const float* __restrict__ scale1, const float* __restrict__ shift1,
    const unsigned short* __restrict__ w2bf, const float* __restrict__ b2,
    unsigned short* __restrict__ y2T, float* __restrict__ part2)
{
    __shared__ float w1s[224];
    __shared__ float s1s[32], f1s[32], b1s[32];
    __shared__ __align__(16) unsigned short a1T[262 * 32];
    __shared__ __align__(16) unsigned short ws2[7 * 64 * 32];
    __shared__ float st[64], sq[64];
    const int n = blockIdx.x;
    const int tid = threadIdx.x;

    if (tid < 224) w1s[tid] = w1[tid];
    if (tid < 32) { s1s[tid] = scale1[tid]; f1s[tid] = shift1[tid]; b1s[tid] = b1[tid]; }
    if (tid < 64) { st[tid] = 0.f; sq[tid] = 0.f; }
    #pragma unroll
    for (int i = 0; i < 7; ++i) {
        int idx = i * 256 + tid;            // [0,1792)
        int k = idx >> 8, rest = idx & 255;
        int c2 = rest >> 2, h = rest & 3;
        *(v8s*)&ws2[(k * 64 + c2) * 32 + ((h ^ (c2 & 3)) << 3)] = *(const v8s*)&w2bf[idx * 8];
    }
    __syncthreads();

    const int cp = tid & 15;            // c1 pair: channels 2cp, 2cp+1
    const int rg = tid >> 4;            // row group 0..15
    const int tt0 = rg * 17;
    float wra[7], wrb[7];
    #pragma unroll
    for (int k = 0; k < 7; ++k) { wra[k] = w1s[(2 * cp) * 7 + k]; wrb[k] = w1s[(2 * cp + 1) * 7 + k]; }
    const float bca = b1s[2 * cp], s1a = s1s[2 * cp], f1a = f1s[2 * cp];
    const float bcb = b1s[2 * cp + 1], s1b = s1s[2 * cp + 1], f1b = f1s[2 * cp + 1];
    const int wblk = (cp >> 2);          // a1T write 16B-block index (pre-swizzle)
    const int wsub = (cp & 3) << 1;      // short offset within block

    const int lane = tid & 63, wv = tid >> 6;
    const int m = lane & 15, kg = lane >> 4;
    const int kgx = kg ^ (m & 3);        // ws2 read: row&3 == m&3, constant per lane
    const float bias[4] = { b2[m], b2[16 + m], b2[32 + m], b2[48 + m] };
    float scr[4] = {0.f, 0.f, 0.f, 0.f}, qcr[4] = {0.f, 0.f, 0.f, 0.f};

    for (int tc = 0; tc < 4; ++tc) {
        const int t0 = tc * 256;
        const int tb0 = t0 - 3 + tt0;
        float xv[24];
        if ((tc == 0 && rg == 0) || (tc == 3 && rg >= 13)) {
            #pragma unroll
            for (int j = 0; j < 24; ++j) {
                int t = tb0 + j;
                xv[j] = (t >= 0 && t < TIN) ? x[n * TIN + t] : 0.f;
            }
        } else {
            #pragma unroll
            for (int j = 0; j < 6; ++j)
                *(float4*)&xv[4 * j] = *(const float4*)&x[n * TIN + tb0 + 4 * j];
        }
        __syncthreads();    // prev chunk's a1T reads done
        #pragma unroll
        for (int o = 0; o < 17; ++o) {
            const int tt = tt0 + o;
            if (tt < 262) {
                float ra = bca, rb = bcb;
                #pragma unroll
                for (int k = 0; k < 7; ++k) {
                    ra = fmaf(xv[o + k], wra[k], ra);
                    rb = fmaf(xv[o + k], wrb[k], rb);
                }
                float va = fmaxf(fmaf(ra, s1a, f1a), 0.f);
                float vb = fmaxf(fmaf(rb, s1b, f1b), 0.f);
                *(unsigned*)&a1T[tt * 32 + ((wblk ^ (tt & 3)) << 3) + wsub] = pack_bf2(va, vb);
            }
        }
        __syncthreads();

        v4f acc[4][4];
        #pragma unroll
        for (int a = 0; a < 4; ++a)
            #pragma unroll
            for (int b = 0; b < 4; ++b)
                #pragma unroll
                for (int r = 0; r < 4; ++r) acc[a][b][r] = 0.f;

        #pragma unroll
        for (int k = 0; k < 7; ++k) {
            const int abk = kg ^ ((m + k) & 3);   // a1T read block: row&3 == (m+k)&3
            v8s af[4], bf[4];
            #pragma unroll
            for (int mt = 0; mt < 4; ++mt)
                af[mt] = *(const v8s*)&a1T[(wv * 64 + mt * 16 + m + k) * 32 + (abk << 3)];
            #pragma unroll
            for (int nt = 0; nt < 4; ++nt)
                bf[nt] = *(const v8s*)&ws2[(k * 64 + nt * 16 + m) * 32 + (kgx << 3)];
            #pragma unroll
            for (int mt = 0; mt < 4; ++mt)
                #pragma unroll
                for (int nt = 0; nt < 4; ++nt)
                    acc[mt][nt] = __builtin_amdgcn_mfma_f32_16x16x32_bf16(af[mt], bf[nt], acc[mt][nt], 0, 0, 0);
        }

        // epilogue on RAW acc (bias folded at partial write): stats + pool store
        if (tc < 3) {
            #pragma unroll
            for (int nt = 0; nt < 4; ++nt) {
                const int c2 = nt * 16 + m;
                #pragma unroll
                for (int mt = 0; mt < 4; ++mt) {
                    const int tb = t0 + wv * 64 + mt * 16 + kg * 4;
                    float praw = (acc[mt][nt][0] + acc[mt][nt][1]) + (acc[mt][nt][2] + acc[mt][nt][3]);
                    scr[nt] += praw;
                    qcr[nt] = fmaf(acc[mt][nt][0], acc[mt][nt][0], qcr[nt]);
                    qcr[nt] = fmaf(acc[mt][nt][1], acc[mt][nt][1], qcr[nt]);
                    qcr[nt] = fmaf(acc[mt][nt][2], acc[mt][nt][2], qcr[nt]);
                    qcr[nt] = fmaf(acc[mt][nt][3], acc[mt][nt][3], qcr[nt]);
                    y2T[(n * 248 + (tb >> 2)) * 64 + c2] = f2bf(fmaf(praw, 0.25f, bias[nt]));
                }
            }
        } else {
            #pragma unroll
            for (int nt = 0; nt < 4; ++nt) {
                const int c2 = nt * 16 + m;
                #pragma unroll
                for (int mt = 0; mt < 4; ++mt) {
                    const int tb = t0 + wv * 64 + mt * 16 + kg * 4;
                    float praw = 0.f;
                    #pragma unroll
                    for (int r = 0; r < 4; ++r) {
                        float v = acc[mt][nt][r];
                        praw += v;
                        if (tb + r < 994) { scr[nt] += v; qcr[nt] = fmaf(v, v, qcr[nt]); }
                    }
                    if (tb < 992)
                        y2T[(n * 248 + (tb >> 2)) * 64 + c2] = f2bf(fmaf(praw, 0.25f, bias[nt]));
                }
            }
        }
    }
    #pragma unroll
    for (int nt = 0; nt < 4; ++nt) {
        float sc = scr[nt], qc = qcr[nt];
        sc += __shfl_xor(sc, 16, 64); qc += __shfl_xor(qc, 16, 64);
        sc += __shfl_xor(sc, 32, 64); qc += __shfl_xor(qc, 32, 64);
        if (kg == 0) { atomicAdd(&st[nt * 16 + m], sc); atomicAdd(&sq[nt * 16 + m], qc); }
    }
    __syncthreads();
    if (tid < 64) {
        // fold bias into stats: sum_t(v+b) = S + 994 b ; sum_t(v+b)^2 = Q + 2bS + 994 b^2
        const float bb = b2[tid];
        const float S = st[tid], Q = sq[tid];
        part2[n * 128 + tid] = S + 994.f * bb;
        part2[n * 128 + 64 + tid] = fmaf(2.f * bb, S, Q) + 994.f * bb * bb;
    }
}

// ---------------------------------------------------------------- conv3 MFMA: ONE block per n, a2T staged once, 4 weight segments
__global__ __launch_bounds__(256, 2) void k_conv3(
    const unsigned short* __restrict__ y2T, const float* __restrict__ scale2, const float* __restrict__ shift2,
    const unsigned short* __restrict__ w3bf, const float* __restrict__ b3,
    unsigned short* __restrict__ y3b, float* __restrict__ part3)
{
    __shared__ __align__(16) unsigned short a2T[262 * 72];
    __shared__ __align__(16) unsigned short ws3[7 * 64 * 32];
    __shared__ float s2s[64], f2s[64];
    __shared__ float st[128], sq[128];
    const int n = blockIdx.x;
    const int tid = threadIdx.x;
    if (tid < 64) { s2s[tid] = scale2[tid]; f2s[tid] = shift2[tid]; }
    if (tid < 128) { st[tid] = 0.f; sq[tid] = 0.f; }
    __syncthreads();

    // stage a2T[tt][c1] = bf16(relu(bn2(y2T[n][tt][c1]))), rows >= 248 zeroed (once per n)
    #pragma unroll
    for (int i = 0; i < 17; ++i) {
        int idx = i * 256 + tid;            // [0,4192) = 262*16
        if (idx < 4192) {
            int tt = idx >> 4, gq = idx & 15;
            uint2 o = make_uint2(0u, 0u);
            if (tt < 248) {
                ushort4 u = *(const ushort4*)&y2T[(n * 248 + tt) * 64 + gq * 4];
                float v0 = fmaxf(fmaf(bf2f(u.x), s2s[gq * 4 + 0], f2s[gq * 4 + 0]), 0.f);
                float v1 = fmaxf(fmaf(bf2f(u.y), s2s[gq * 4 + 1], f2s[gq * 4 + 1]), 0.f);
                float v2 = fmaxf(fmaf(bf2f(u.z), s2s[gq * 4 + 2], f2s[gq * 4 + 2]), 0.f);
                float v3 = fmaxf(fmaf(bf2f(u.w), s2s[gq * 4 + 3], f2s[gq * 4 + 3]), 0.f);
                o.x = pack_bf2(v0, v1);
                o.y = pack_bf2(v2, v3);
            }
            *(uint2*)&a2T[tt * 72 + gq * 4] = o;
        }
    }

    const int lane = tid & 63, wv = tid >> 6;
    const int m = lane & 15, kg = lane >> 4;
    const int kgx = kg ^ (m & 3);        // ws3 read block: row&3 == m&3
    // per-thread ws3 staging decomposition (7 v8s per segment), XOR-swizzled dest
    v8s wreg[7];
    int kidx[7], dsoff[7];
    #pragma unroll
    for (int i = 0; i < 7; ++i) {
        int idx = i * 256 + tid;
        int k = idx >> 8, rest = idx & 255;
        int c2l = rest >> 2, h = rest & 3;
        kidx[i] = (k * 128 + c2l) * 32 + h * 8;          // src offset within [ch][*]: ch stride = 7*128*32
        dsoff[i] = (k * 64 + c2l) * 32 + ((h ^ (c2l & 3)) << 3);
    }
    // prefetch segment 0 (c2h=0, ch=0)
    #pragma unroll
    for (int i = 0; i < 7; ++i) wreg[i] = *(const v8s*)&w3bf[kidx[i]];

    v4f acc[4][4];
    for (int seg = 0; seg < 4; ++seg) {
        const int c2h = seg >> 1, ch = seg & 1;
        __syncthreads();   // a2T staged (seg 0) / prev ws3 reads done
        #pragma unroll
        for (int i = 0; i < 7; ++i) *(v8s*)&ws3[dsoff[i]] = wreg[i];
        if (seg < 3) {
            const int nc2h = (seg + 1) >> 1, nch = (seg + 1) & 1;
            const long base = (long)nch * (7 * 128 * 32) + nc2h * (64 * 32);
            #pragma unroll
            for (int i = 0; i < 7; ++i) wreg[i] = *(const v8s*)&w3bf[base + kidx[i]];
        }
        __syncthreads();
        if (ch == 0) {
            #pragma unroll
            for (int a = 0; a < 4; ++a)
                #pragma unroll
                for (int b = 0; b < 4; ++b)
                    #pragma unroll
                    for (int r = 0; r < 4; ++r) acc[a][b][r] = 0.f;
        }
        #pragma unroll
        for (int k = 0; k < 7; ++k) {
            v8s af[4], bf[4];
            #pragma unroll
            for (int mt = 0; mt < 4; ++mt)
                af[mt] = *(const v8s*)&a2T[(wv * 64 + mt * 16 + m + k) * 72 + ch * 32 + kg * 8];
            #pragma unroll
            for (int nt = 0; nt < 4; ++nt)
                bf[nt] = *(const v8s*)&ws3[(k * 64 + nt * 16 + m) * 32 + (kgx << 3)];
            #pragma unroll
            for (int mt = 0; mt < 4; ++mt)
                #pragma unroll
                for (int nt = 0; nt < 4; ++nt)
                    acc[mt][nt] = __builtin_amdgcn_mfma_f32_16x16x32_bf16(af[mt], bf[nt], acc[mt][nt], 0, 0, 0);
        }
        if (ch == 1) {
            // epilogue for this c2h on RAW acc (bias folded at partial write)
            #pragma unroll
            for (int nt = 0; nt < 4; ++nt) {
                const int c2l = nt * 16 + m;
                const int c2 = c2h * 64 + c2l;
                const float bb = b3[c2];
                float scr = 0.f, qcr = 0.f;
                #pragma unroll
                for (int mt = 0; mt < 4; ++mt) {
                    const int ts = wv * 64 + mt * 16 + kg * 4;
                    if (!(mt == 3 && wv == 3)) {
                        float praw = (acc[mt][nt][0] + acc[mt][nt][1]) + (acc[mt][nt][2] + acc[mt][nt][3]);
                        scr += praw;
                        qcr = fmaf(acc[mt][nt][0], acc[mt][nt][0], qcr);
                        qcr = fmaf(acc[mt][nt][1], acc[mt][nt][1], qcr);
                        qcr = fmaf(acc[mt][nt][2], acc[mt][nt][2], qcr);
                        qcr = fmaf(acc[mt][nt][3], acc[mt][nt][3], qcr);
                        y3b[(n * 128 + c2) * 60 + (ts >> 2)] = f2bf(fmaf(praw, 0.25f, bb));
                    } else {
                        #pragma unroll
                        for (int r = 0; r < 4; ++r) {
                            float v = acc[mt][nt][r];
                            if (ts + r < 242) { scr += v; qcr = fmaf(v, v, qcr); }
                        }
                    }
                }
                scr += __shfl_xor(scr, 16, 64); qcr += __shfl_xor(qcr, 16, 64);
                scr += __shfl_xor(scr, 32, 64); qcr += __shfl_xor(qcr, 32, 64);
                if (kg == 0) { atomicAdd(&st[c2], scr); atomicAdd(&sq[c2], qcr); }
            }
        }
    }
    __syncthreads();
    if (tid < 128) {
        const float bb = b3[tid];
        const float S = st[tid], Q = sq[tid];
        part3[(long)n * 256 + tid] = S + 242.f * bb;
        part3[(long)n * 256 + 128 + tid] = fmaf(2.f * bb, S, Q) + 242.f * bb * bb;
    }
}

// ---------------------------------------------------------------- h0 = bf16(relu(bn3(y3b)) + pe), ushort4 vectorized (4 | 60 -> c uniform per quad)
__global__ __launch_bounds__(256) void k_h0(
    const unsigned short* __restrict__ y3b, const float* __restrict__ scale3, const float* __restrict__ shift3,
    const float* __restrict__ pe, unsigned short* __restrict__ h0b)
{
    const int n = blockIdx.y;
    const int idx = blockIdx.x * 256 + threadIdx.x;   // quad index < 1920
    if (idx < 1920) {
        const int c = idx / 15;
        const float sc = scale3[c], sh = shift3[c], pv = pe[n * 128 + c];
        ushort4 u = *(const ushort4*)&y3b[n * FLATD + idx * 4];
        ushort4 o;
        o.x = f2bf(fmaxf(fmaf(bf2f(u.x), sc, sh), 0.f) + pv);
        o.y = f2bf(fmaxf(fmaf(bf2f(u.y), sc, sh), 0.f) + pv);
        o.z = f2bf(fmaxf(fmaf(bf2f(u.z), sc, sh), 0.f) + pv);
        o.w = f2bf(fmaxf(fmaf(bf2f(u.w), sc, sh), 0.f) + pv);
        *(ushort4*)&h0b[n * FLATD + idx * 4] = o;
    }
}

// ---------------------------------------------------------------- CSR build (scan + fill; count lives in k_aux)
__global__ __launch_bounds__(256) void k_csr_scan(
    const int* __restrict__ cnt, int* __restrict__ rowptr,
    float* __restrict__ dinv, float* __restrict__ invd)
{
    __shared__ int ps[256];
    const int tid = threadIdx.x;
    const int base = tid * 8;
    int v[8]; int s = 0;
    #pragma unroll
    for (int i = 0; i < 8; ++i) { v[i] = cnt[base + i]; s += v[i]; }
    ps[tid] = s;
    __syncthreads();
    for (int off = 1; off < 256; off <<= 1) {
        int t = (tid >= off) ? ps[tid - off] : 0;
        __syncthreads();
        ps[tid] += t;
        __syncthreads();
    }
    int run = ps[tid] - s;   // exclusive prefix
    #pragma unroll
    for (int i = 0; i < 8; ++i) {
        rowptr[base + i] = run;
        run += v[i];
        float d = (float)v[i] + 1.0f;
        dinv[base + i] = rsqrtf(d);
        invd[base + i] = 1.0f / d;
    }
    if (tid == 255) rowptr[2048] = run;
}
__global__ void k_csr_fill(const int* __restrict__ ei, const int* __restrict__ rowptr,
                           int* __restrict__ cursor, const float* __restrict__ dinv,
                           int* __restrict__ csr_src, float* __restrict__ csr_coef)
{
    int e = blockIdx.x * 256 + threadIdx.x;
    if (e < NEDGE) {
        int s = ei[e], d = ei[NEDGE + e];
        int pos = rowptr[d] + atomicAdd(&cursor[d], 1);
        csr_src[pos] = s;
        csr_coef[pos] = dinv[s] * dinv[d];
    }
}

// ---------------------------------------------------------------- bf16 MFMA GEMM: plain stores into per-slice buffers
__global__ __launch_bounds__(256) void k_gemm_mfma(
    const unsigned short* __restrict__ A, const unsigned short* __restrict__ BT,
    float* __restrict__ C, int K, int Kslice)
{
    __shared__ __align__(16) unsigned short As[128 * 40];
    __shared__ __align__(16) unsigned short Bs[128 * 40];
    const int tid = threadIdx.x;
    const int m0 = blockIdx.x * 128, n0 = blockIdx.y * 128;
    const int k0 = blockIdx.z * Kslice, kend = k0 + Kslice;
    float* Cd = C + (long)blockIdx.z * (NN * EMBD);
    const int lane = tid & 63, wvv = tid >> 6;
    const int wm = (wvv & 1) * 64, wn = (wvv >> 1) * 64;
    const int m = lane & 15, kg = lane >> 4;
    const int sr = tid >> 1, sh = (tid & 1) * 16;
    v4f acc[4][4];
    #pragma unroll
    for (int a = 0; a < 4; ++a)
        #pragma unroll
        for (int b = 0; b < 4; ++b)
            #pragma unroll
            for (int r = 0; r < 4; ++r) acc[a][b][r] = 0.f;

    for (int kt = k0; kt < kend; kt += 32) {
        const unsigned short* ap = &A[(long)(m0 + sr) * K + kt + sh];
        v8s a0 = *(const v8s*)ap;
        v8s a1 = *(const v8s*)(ap + 8);
        const unsigned short* bp = &BT[(long)(n0 + sr) * K + kt + sh];
        v8s b0 = *(const v8s*)bp;
        v8s b1 = *(const v8s*)(bp + 8);
        __syncthreads();
        *(v8s*)&As[sr * 40 + sh] = a0;
        *(v8s*)&As[sr * 40 + sh + 8] = a1;
        *(v8s*)&Bs[sr * 40 + sh] = b0;
        *(v8s*)&Bs[sr * 40 + sh + 8] = b1;
        __syncthreads();
        v8s af[4], bf[4];
        #pragma unroll
        for (int mt = 0; mt < 4; ++mt) af[mt] = *(const v8s*)&As[(wm + mt * 16 + m) * 40 + kg * 8];
        #pragma unroll
        for (int nt = 0; nt < 4; ++nt) bf[nt] = *(const v8s*)&Bs[(wn + nt * 16 + m) * 40 + kg * 8];
        #pragma unroll
        for (int mt = 0; mt < 4; ++mt)
            #pragma unroll
            for (int nt = 0; nt < 4; ++nt)
                acc[mt][nt] = __builtin_amdgcn_mfma_f32_16x16x32_bf16(af[mt], bf[nt], acc[mt][nt], 0, 0, 0);
    }
    #pragma unroll
    for (int mt = 0; mt < 4; ++mt) {
        const int row = m0 + wm + mt * 16 + kg * 4;
        #pragma unroll
        for (int nt = 0; nt < 4; ++nt) {
            const int col = n0 + wn + nt * 16 + m;
            #pragma unroll
            for (int r = 0; r < 4; ++r)
                Cd[(long)(row + r) * EMBD + col] = acc[mt][nt][r];
        }
    }
}

// ---------------------------------------------------------------- combine split-K partials
__global__ __launch_bounds__(256) void k_combine(float* __restrict__ P, int nsl)
{
    long i = (long)(blockIdx.x * 256 + threadIdx.x) * 4;
    float4 a = *(float4*)&P[i];
    for (int s = 1; s < nsl; ++s) {
        float4 c = *(const float4*)&P[(long)s * 1572864 + i];
        a.x += c.x; a.y += c.y; a.z += c.z; a.w += c.w;
    }
    *(float4*)&P[i] = a;
}

// ---------------------------------------------------------------- fused CSR gather + gcn finalize (bf16 out)
__global__ __launch_bounds__(256) void k_gcn_gather(
    const float* __restrict__ P, const int* __restrict__ rowptr,
    const int* __restrict__ csr_src, const float* __restrict__ csr_coef,
    const float* __restrict__ invd, const float* __restrict__ b,
    unsigned short* __restrict__ Hb)
{
    const int n = blockIdx.x, tid = threadIdx.x;
    const int beg = rowptr[n], end = rowptr[n + 1];
    float a0 = 0.f, a1 = 0.f, a2 = 0.f;
    for (int j = beg; j < end; ++j) {
        const int s = csr_src[j];
        const float cf = csr_coef[j];
        const float* Pr = P + (long)s * EMBD;
        a0 = fmaf(cf, Pr[tid], a0);
        a1 = fmaf(cf, Pr[tid + 256], a1);
        a2 = fmaf(cf, Pr[tid + 512], a2);
    }
    const float inv = invd[n];
    const float* Pn = P + (long)n * EMBD;
    float v0 = fmaxf(fmaf(Pn[tid], inv, a0) + b[tid], 0.f);
    float v1 = fmaxf(fmaf(Pn[tid + 256], inv, a1) + b[tid + 256], 0.f);
    float v2 = fmaxf(fmaf(Pn[tid + 512], inv, a2) + b[tid + 512], 0.f);
    Hb[(long)n * EMBD + tid] = f2bf(v0);
    Hb[(long)n * EMBD + tid + 256] = f2bf(v1);
    Hb[(long)n * EMBD + tid + 512] = f2bf(v2);
}

// ---------------------------------------------------------------- pool + dense + log_softmax (bf16 input)
__global__ __launch_bounds__(256) void k_head(
    const unsigned short* __restrict__ Hb, const float* __restrict__ dw, const float* __restrict__ db,
    float* __restrict__ out)
{
    __shared__ float ls[4];
    const int b = blockIdx.x, tid = threadIdx.x;
    if (tid < 4) ls[tid] = 0.f;
    __syncthreads();
    float pl0 = 0.f, pl1 = 0.f, pl2 = 0.f, pl3 = 0.f;
    for (int fo = 0; fo < 3; ++fo) {
        const int f = tid + 256 * fo;
        float s = 0.f;
        for (int r = 0; r < 64; ++r) s += bf2f(Hb[(b * 64 + r) * EMBD + f]);
        s *= (1.f / 64.f);
        pl0 = fmaf(s, dw[f * 4 + 0], pl0);
        pl1 = fmaf(s, dw[f * 4 + 1], pl1);
        pl2 = fmaf(s, dw[f * 4 + 2], pl2);
        pl3 = fmaf(s, dw[f * 4 + 3], pl3);
    }
    #pragma unroll
    for (int off = 32; off > 0; off >>= 1) {
        pl0 += __shfl_down(pl0, off, 64);
        pl1 += __shfl_down(pl1, off, 64);
        pl2 += __shfl_down(pl2, off, 64);
        pl3 += __shfl_down(pl3, off, 64);
    }
    if ((tid & 63) == 0) {
        atomicAdd(&ls[0], pl0); atomicAdd(&ls[1], pl1);
        atomicAdd(&ls[2], pl2); atomicAdd(&ls[3], pl3);
    }
    __syncthreads();
    if (tid == 0) {
        float l0 = ls[0] + db[0], l1 = ls[1] + db[1], l2 = ls[2] + db[2], l3 = ls[3] + db[3];
        float m = fmaxf(fmaxf(l0, l1), fmaxf(l2, l3));
        float sum = expf(l0 - m) + expf(l1 - m) + expf(l2 - m) + expf(l3 - m);
        float lse = logf(sum);
        out[b * 4 + 0] = l0 - m - lse;
        out[b * 4 + 1] = l1 - m - lse;
        out[b * 4 + 2] = l2 - m - lse;
        out[b * 4 + 3] = l3 - m - lse;
    }
}

// ================================================================ launch
extern "C" void kernel_launch(void* const* d_in, const int* in_sizes, int n_in,
                              void* d_out, int out_size, void* d_ws, size_t ws_size,
                              hipStream_t stream)
{
    (void)in_sizes; (void)n_in; (void)out_size; (void)ws_size;
    const float* x   = (const float*)d_in[0];
    const float* pos = (const float*)d_in[1];
    const int*   ei  = (const int*)d_in[2];
    const float* w1  = (const float*)d_in[4];
    const float* b1  = (const float*)d_in[5];
    const float* g1  = (const float*)d_in[6];
    const float* bt1 = (const float*)d_in[7];
    const float* w2  = (const float*)d_in[8];
    const float* b2  = (const float*)d_in[9];
    const float* g2  = (const float*)d_in[10];
    const float* bt2 = (const float*)d_in[11];
    const float* w3  = (const float*)d_in[12];
    const float* b3  = (const float*)d_in[13];
    const float* g3  = (const float*)d_in[14];
    const float* bt3 = (const float*)d_in[15];
    const float* pw1 = (const float*)d_in[16];
    const float* pb1 = (const float*)d_in[17];
    const float* pw2 = (const float*)d_in[18];
    const float* pb2 = (const float*)d_in[19];
    const float* gw1 = (const float*)d_in[20];
    const float* gb1 = (const float*)d_in[21];
    const float* gw2 = (const float*)d_in[22];
    const float* gb2 = (const float*)d_in[23];
    const float* dw  = (const float*)d_in[24];
    const float* db  = (const float*)d_in[25];

    float* wsf = (float*)d_ws;
    // y2T bf16 occupies floats [0, 16252928) until conv3; then reused for GCN buffers.
    // pe MUST live outside [0, 16252928): k_prep writes it BEFORE conv2 overwrites y2T.
    unsigned short* y2T = (unsigned short*)wsf;
    float* P0  = wsf;                                           // 8 slices x 1,572,864 f
    unsigned short* X3b = (unsigned short*)(wsf + 12582912);    // 1,572,864 bf16
    unsigned short* y3b = (unsigned short*)(wsf + 16252928);    // 15,728,640 bf16 -> [16252928, 24117248)
    float* part1 = wsf + 24117248;                              // 35*512 = 17,920
    float* part2 = wsf + 24150016;                              // 262,144
    float* part3 = wsf + 24412160;                              // 524,288 -> end 24936448
    unsigned short* h0b = (unsigned short*)(wsf + 24936448);    // 15,728,640 bf16 -> [24936448, 32800768)
    unsigned short* gw1T = (unsigned short*)(wsf + 32800768);   // 5,898,240 bf16
    unsigned short* gw2T = (unsigned short*)(wsf + 35749888);   // 589,824 bf16
    unsigned short* w2bf = (unsigned short*)(wsf + 36044800);   // 14,336 bf16
    unsigned short* w3bf = (unsigned short*)(wsf + 36051968);   // 57,344 bf16
    float* fb = wsf + 36081536;                                 // 448 f
    float* scale1 = fb,       *shift1 = fb + 32;
    float* scale2 = fb + 64,  *shift2 = fb + 128;
    float* scale3 = fb + 192, *shift3 = fb + 320;
    float* dinv = wsf + 36081984;                               // 2048
    float* invd = wsf + 36084032;                               // 2048
    int* cnt    = (int*)(wsf + 36086080);                       // 2048
    int* cursor = (int*)(wsf + 36088128);                       // 2048 (contiguous with cnt)
    int* rowptr = (int*)(wsf + 36090176);                       // 2049
    int* csr_src = (int*)(wsf + 36092240);                      // 32768
    float* csr_coef = wsf + 36125008;                           // 32768 -> end 36157776
    float* pe  = wsf + 36157776;                                // 262,144 f (tail; survives conv2/conv3)

    // mega-prep: cvt w2/w3, transpose gw1/gw2, zero cnt+cursor, pos-MLP, x-moments
    k_prep<<<2648, 256, 0, stream>>>(w2, w2bf, w3, w3bf, gw1, gw1T, gw2, gw2T,
                                     cnt, pos, pw1, pb1, pw2, pb2, pe, x, part1);
    // aux: bn1 finalize (block 0) + CSR count (blocks 1..128)
    k_aux<<<129, 256, 0, stream>>>(part1, w1, b1, g1, bt1, scale1, shift1, ei, cnt);
    k_csr_scan<<<1, 256, 0, stream>>>(cnt, rowptr, dinv, invd);
    k_csr_fill<<<128, 256, 0, stream>>>(ei, rowptr, cursor, dinv, csr_src, csr_coef);

    // conv pipeline
    k_conv2<<<2048, 256, 0, stream>>>(x, w1, b1, scale1, shift1, w2bf, b2, y2T, part2);
    k_reduce_stats<<<64, 256, 0, stream>>>(part2, g2, bt2, scale2, shift2, 2048, 128, 64, 1.f / (2048.f * 994.f));
    k_conv3<<<2048, 256, 0, stream>>>(y2T, scale2, shift2, w3bf, b3, y3b, part3);
    k_reduce_stats<<<128, 256, 0, stream>>>(part3, g3, bt3, scale3, shift3, 2048, 256, 128, 1.f / (2048.f * 242.f));
    k_h0<<<dim3(8, 2048), 256, 0, stream>>>(y3b, scale3, shift3, pe, h0b);

    // GCN layer 1: split-K=8 GEMM -> combine -> gather+fin (bf16)
    k_gemm_mfma<<<dim3(16, 6, 8), 256, 0, stream>>>(h0b, gw1T, P0, FLATD, FLATD / 8);
    k_combine<<<1536, 256, 0, stream>>>(P0, 8);
    k_gcn_gather<<<2048, 256, 0, stream>>>(P0, rowptr, csr_src, csr_coef, invd, gb1, X3b);

    // GCN layer 2: split-K=2 GEMM -> combine -> gather+fin
    k_gemm_mfma<<<dim3(16, 6, 2), 256, 0, stream>>>(X3b, gw2T, P0, EMBD, EMBD / 2);
    k_combine<<<1536, 256, 0, stream>>>(P0, 2);
    k_gcn_gather<<<2048, 256, 0, stream>>>(P0, rowptr, csr_src, csr_coef, invd, gb2, X3b);

    k_head<<<32, 256, 0, stream>>>(X3b, dw, db, (float*)d_out);
}

// Round 9
// 446.365 us; speedup vs baseline: 1.0779x; 1.0779x over previous
//
#include <hip/hip_runtime.h>
#include <hip/hip_bf16.h>

#define NN    2048
#define TIN   1000
#define NEDGE 32768
#define EMBD  768
#define FLATD 7680
#define BNEPS 1e-5f

typedef __attribute__((ext_vector_type(8))) short v8s;
typedef __attribute__((ext_vector_type(4))) float v4f;

__device__ inline unsigned short f2bf(float f) {
    unsigned u = __float_as_uint(f);
    u += 0x7fff + ((u >> 16) & 1);
    return (unsigned short)(u >> 16);
}
__device__ inline float bf2f(unsigned short h) {
    return __uint_as_float(((unsigned)h) << 16);
}
__device__ inline unsigned pack_bf2(float a, float b) {
    __hip_bfloat162 pk = __float22bfloat162_rn(make_float2(a, b));
    return *(unsigned*)&pk;
}

// ---------------------------------------------------------------- mega-prep: w2/w3 cvt, gw1/gw2 transpose, cnt zero, pos-MLP, x-moments
__global__ __launch_bounds__(256) void k_prep(
    const float* __restrict__ w2, unsigned short* __restrict__ w2bf,
    const float* __restrict__ w3, unsigned short* __restrict__ w3bf,
    const float* __restrict__ gw1, unsigned short* __restrict__ gw1T,
    const float* __restrict__ gw2, unsigned short* __restrict__ gw2T,
    int* __restrict__ cntz,
    const float* __restrict__ pos, const float* __restrict__ pw1, const float* __restrict__ pb1,
    const float* __restrict__ pw2, const float* __restrict__ pb2, float* __restrict__ pe,
    const float* __restrict__ x, float* __restrict__ part1)
{
    __shared__ float smem[4 * 1008 + 64];
    const int b = blockIdx.x, tid = threadIdx.x;
    if (b < 56) {
        int idx = b * 256 + tid;            // 14336 = 7*64*32
        int c1 = idx & 31, c2 = (idx >> 5) & 63, k = idx >> 11;
        w2bf[idx] = f2bf(w2[(c2 * 32 + c1) * 7 + k]);
    } else if (b < 280) {
        int idx = (b - 56) * 256 + tid;     // 57344
        int c1l = idx & 31, c2 = (idx >> 5) & 127, t = idx >> 12;
        int k = t % 7, ch = t / 7;
        w3bf[idx] = f2bf(w3[(c2 * 64 + ch * 32 + c1l) * 7 + k]);
    } else if (b < 1864) {
        // fp32 [R][C] -> bf16 [C][R], 64x64 tiles
        const float* src; unsigned short* dst; int R, Cc, t;
        if (b < 1720) { src = gw1; dst = gw1T; R = FLATD; Cc = EMBD; t = b - 280; }
        else          { src = gw2; dst = gw2T; R = EMBD;  Cc = EMBD; t = b - 1720; }
        const int r0 = (t / 12) * 64, c0 = (t % 12) * 64;
        unsigned short* tile = (unsigned short*)smem;   // [64][66]
        #pragma unroll
        for (int i = 0; i < 16; ++i) {
            int idx = i * 256 + tid;
            int r = idx >> 6, c = idx & 63;
            tile[r * 66 + c] = f2bf(src[(long)(r0 + r) * Cc + c0 + c]);
        }
        __syncthreads();
        #pragma unroll
        for (int i = 0; i < 16; ++i) {
            int idx = i * 256 + tid;
            int c = idx >> 6, r = idx & 63;
            dst[(long)(c0 + c) * R + r0 + r] = tile[r * 66 + c];
        }
    } else if (b < 1880) {
        cntz[(b - 1864) * 256 + tid] = 0;   // cnt + cursor (4096 ints)
    } else if (b < 2136) {
        // positional MLP: 8 n per block, 128 active threads
        float* hid = smem;
        const int t = b - 1880;
        float w10 = 0.f, w11 = 0.f, w12 = 0.f, b1j = 0.f, b2j = 0.f;
        if (tid < 128) {
            w10 = pw1[tid]; w11 = pw1[128 + tid]; w12 = pw1[256 + tid];
            b1j = pb1[tid]; b2j = pb2[tid];
        }
        for (int nl = 0; nl < 8; ++nl) {
            const int n = t * 8 + nl;
            float h = 0.f;
            if (tid < 128) {
                float p0 = pos[n * 3], p1 = pos[n * 3 + 1], p2 = pos[n * 3 + 2];
                h = fmaxf(fmaf(p0, w10, fmaf(p1, w11, fmaf(p2, w12, b1j))), 0.f);
            }
            __syncthreads();
            if (tid < 128) hid[tid] = h;
            __syncthreads();
            if (tid < 128) {
                float a = b2j;
                #pragma unroll 8
                for (int i = 0; i < 128; ++i) a = fmaf(hid[i], pw2[i * 128 + tid], a);
                pe[n * 128 + tid] = a;
            }
        }
    } else {
        // x moments for analytic BN1 (512 blocks)
        float* xs = smem;
        float* red = &smem[4032];
        const int n0 = (b - 2136) * 4;
        for (int idx = tid; idx < 4 * 1008; idx += 256) {
            int r = idx / 1008, p = idx % 1008;
            int t = p - 3;
            xs[idx] = (t >= 0 && t < TIN) ? x[(n0 + r) * TIN + t] : 0.f;
        }
        if (tid < 35) red[tid] = 0.f;
        __syncthreads();
        float S[7], C[28];
        #pragma unroll
        for (int i = 0; i < 7; ++i) S[i] = 0.f;
        #pragma unroll
        for (int i = 0; i < 28; ++i) C[i] = 0.f;
        for (int r = 0; r < 4; ++r) {
            #pragma unroll
            for (int i2 = 0; i2 < 4; ++i2) {
                const int t = tid + 256 * i2;
                if (t < TIN) {
                    float v[7];
                    #pragma unroll
                    for (int k = 0; k < 7; ++k) v[k] = xs[r * 1008 + t + k];
                    int p = 0;
                    #pragma unroll
                    for (int i = 0; i < 7; ++i) {
                        S[i] += v[i];
                        #pragma unroll
                        for (int j = i; j < 7; ++j) { C[p] = fmaf(v[i], v[j], C[p]); ++p; }
                    }
                }
            }
        }
        #pragma unroll
        for (int vv = 0; vv < 7; ++vv) {
            float s = S[vv];
            #pragma unroll
            for (int off = 32; off > 0; off >>= 1) s += __shfl_xor(s, off, 64);
            if ((tid & 63) == 0) atomicAdd(&red[vv], s);
        }
        #pragma unroll
        for (int vv = 0; vv < 28; ++vv) {
            float s = C[vv];
            #pragma unroll
            for (int off = 32; off > 0; off >>= 1) s += __shfl_xor(s, off, 64);
            if ((tid & 63) == 0) atomicAdd(&red[7 + vv], s);
        }
        __syncthreads();
        if (tid < 35) part1[tid * 512 + (b - 2136)] = red[tid];
    }
}

// ---------------------------------------------------------------- aux: block 0 = BN1 finalize (exact quadratic form); blocks 1..128 = CSR count
__global__ __launch_bounds__(256) void k_aux(
    const float* __restrict__ part, const float* __restrict__ w1, const float* __restrict__ b1,
    const float* __restrict__ g, const float* __restrict__ bt,
    float* __restrict__ scale, float* __restrict__ shift,
    const int* __restrict__ ei, int* __restrict__ cnt)
{
    const int tid = threadIdx.x;
    if (blockIdx.x != 0) {
        int e = (blockIdx.x - 1) * 256 + tid;
        if (e < NEDGE) atomicAdd(&cnt[ei[NEDGE + e]], 1);
        return;
    }
    __shared__ double SMp[140];
    __shared__ double SM[35];
    if (tid < 140) {
        int v = tid >> 2, l = tid & 3;
        double s = 0.0;
        for (int b = l; b < 512; b += 4) s += (double)part[v * 512 + b];
        SMp[tid] = s;
    }
    __syncthreads();
    if (tid < 35) SM[tid] = SMp[tid * 4] + SMp[tid * 4 + 1] + SMp[tid * 4 + 2] + SMp[tid * 4 + 3];
    __syncthreads();
    if (tid < 32) {
        double wv[7];
        #pragma unroll
        for (int k = 0; k < 7; ++k) wv[k] = (double)w1[tid * 7 + k];
        double m1 = 0.0;
        #pragma unroll
        for (int k = 0; k < 7; ++k) m1 += wv[k] * SM[k];
        double e2 = 0.0;
        int p = 7;
        #pragma unroll
        for (int i = 0; i < 7; ++i)
            #pragma unroll
            for (int j = i; j < 7; ++j) {
                double t = wv[i] * wv[j] * SM[p++];
                e2 += (i == j) ? t : 2.0 * t;
            }
        const double invN = 1.0 / 2048000.0;
        double bc = (double)b1[tid];
        double mean = m1 * invN + bc;
        double E2 = e2 * invN + 2.0 * bc * m1 * invN + bc * bc;
        double var = E2 - mean * mean;
        float rs = rsqrtf((float)var + BNEPS);
        float sc = g[tid] * rs;
        scale[tid] = sc;
        shift[tid] = bt[tid] - (float)mean * sc;
    }
}

// ---------------------------------------------------------------- stats reduce + bn finalize; blocks >= nC do CSR fill
__global__ __launch_bounds__(256) void k_reduce_stats(
    const float* __restrict__ part, const float* __restrict__ g, const float* __restrict__ bt,
    float* __restrict__ scale, float* __restrict__ shift,
    int count, int stride, int sqdelta, float inv_count, int nC,
    const int* __restrict__ ei, const int* __restrict__ rowptr,
    int* __restrict__ cursor, const float* __restrict__ dinv,
    int* __restrict__ csr_src, float* __restrict__ csr_coef)
{
    const int tid = threadIdx.x;
    if (blockIdx.x >= nC) {
        int e = (blockIdx.x - nC) * 256 + tid;
        if (e < NEDGE) {
            int s = ei[e], d = ei[NEDGE + e];
            int pos = rowptr[d] + atomicAdd(&cursor[d], 1);
            csr_src[pos] = s;
            csr_coef[pos] = dinv[s] * dinv[d];
        }
        return;
    }
    __shared__ double ss[4], qq[4];
    const int c = blockIdx.x;
    double s = 0.0, q = 0.0;
    for (int i = tid; i < count; i += 256) {
        s += (double)part[c + (long)i * stride];
        q += (double)part[c + sqdelta + (long)i * stride];
    }
    #pragma unroll
    for (int off = 32; off > 0; off >>= 1) {
        s += __shfl_down(s, off, 64);
        q += __shfl_down(q, off, 64);
    }
    if ((tid & 63) == 0) { ss[tid >> 6] = s; qq[tid >> 6] = q; }
    __syncthreads();
    if (tid == 0) {
        double S = ss[0] + ss[1] + ss[2] + ss[3];
        double Q = qq[0] + qq[1] + qq[2] + qq[3];
        float mm = (float)(S * (double)inv_count);
        float vv = (float)(Q * (double)inv_count) - mm * mm;
        float rs = rsqrtf(vv + BNEPS);
        float sc = g[c] * rs;
        scale[c] = sc;
        shift[c] = bt[c] - mm * sc;
    }
}

// ---------------------------------------------------------------- conv2 MFMA: block per n, 4 chunks of 256t, wave tile 64t x 64c2
// block 2048 = CSR scan (independent work, hides a launch gap)
__global__ __launch_bounds__(256, 3) void k_conv2(
    const float* __restrict__ x, const float* __restrict__ w1, const float* __restrict__ b1,
    const float* __restrict__ scale1, const float* __restrict__ shift1,
    const unsigned short* __restrict__ w2bf, const float* __restrict__ b2,
    unsigned short* __restrict__ y2T, float* __restrict__ part2,
    const int* __restrict__ cnt, int* __restrict__ rowptr,
    float* __restrict__ dinv, float* __restrict__ invd)
{
    const int tid = threadIdx.x;
    if (blockIdx.x == 2048) {
        // CSR scan + degree coefficients
        __shared__ int ps[256];
        const int base = tid * 8;
        int v[8]; int s = 0;
        #pragma unroll
        for (int i = 0; i < 8; ++i) { v[i] = cnt[base + i]; s += v[i]; }
        ps[tid] = s;
        __syncthreads();
        for (int off = 1; off < 256; off <<= 1) {
            int t = (tid >= off) ? ps[tid - off] : 0;
            __syncthreads();
            ps[tid] += t;
            __syncthreads();
        }
        int run = ps[tid] - s;   // exclusive prefix
        #pragma unroll
        for (int i = 0; i < 8; ++i) {
            rowptr[base + i] = run;
            run += v[i];
            float d = (float)v[i] + 1.0f;
            dinv[base + i] = rsqrtf(d);
            invd[base + i] = 1.0f / d;
        }
        if (tid == 255) rowptr[2048] = run;
        return;
    }

    __shared__ float w1s[224];
    __shared__ float s1s[32], f1s[32], b1s[32];
    __shared__ __align__(16) unsigned short a1T[262 * 32];
    __shared__ __align__(16) unsigned short ws2[7 * 64 * 32];
    __shared__ float st[64], sq[64];
    const int n = blockIdx.x;

    if (tid < 224) w1s[tid] = w1[tid];
    if (tid < 32) { s1s[tid] = scale1[tid]; f1s[tid] = shift1[tid]; b1s[tid] = b1[tid]; }
    if (tid < 64) { st[tid] = 0.f; sq[tid] = 0.f; }
    #pragma unroll
    for (int i = 0; i < 7; ++i) {
        int idx = i * 256 + tid;            // [0,1792)
        int k = idx >> 8, rest = idx & 255;
        int c2 = rest >> 2, h = rest & 3;
        *(v8s*)&ws2[(k * 64 + c2) * 32 + h * 8] = *(const v8s*)&w2bf[idx * 8];
    }
    __syncthreads();

    const int cp = tid & 15;            // c1 pair: channels 2cp, 2cp+1
    const int rg = tid >> 4;            // row group 0..15
    const int tt0 = rg * 17;
    float wra[7], wrb[7];
    #pragma unroll
    for (int k = 0; k < 7; ++k) { wra[k] = w1s[(2 * cp) * 7 + k]; wrb[k] = w1s[(2 * cp + 1) * 7 + k]; }
    const float bca = b1s[2 * cp], s1a = s1s[2 * cp], f1a = f1s[2 * cp];
    const float bcb = b1s[2 * cp + 1], s1b = s1s[2 * cp + 1], f1b = f1s[2 * cp + 1];

    const int lane = tid & 63, wv = tid >> 6;
    const int m = lane & 15, kg = lane >> 4;
    const float bias[4] = { b2[m], b2[16 + m], b2[32 + m], b2[48 + m] };
    float scr[4] = {0.f, 0.f, 0.f, 0.f}, qcr[4] = {0.f, 0.f, 0.f, 0.f};

    for (int tc = 0; tc < 4; ++tc) {
        const int t0 = tc * 256;
        const int tb0 = t0 - 3 + tt0;
        float xv[23];
        if ((tc == 0 && rg == 0) || (tc == 3 && rg >= 13)) {
            #pragma unroll
            for (int j = 0; j < 23; ++j) {
                int t = tb0 + j;
                xv[j] = (t >= 0 && t < TIN) ? x[n * TIN + t] : 0.f;
            }
        } else {
            #pragma unroll
            for (int j = 0; j < 23; ++j) xv[j] = x[n * TIN + tb0 + j];
        }
        __syncthreads();    // prev chunk's a1T reads done
        #pragma unroll
        for (int o = 0; o < 17; ++o) {
            const int tt = tt0 + o;
            if (tt < 262) {
                float ra = bca, rb = bcb;
                #pragma unroll
                for (int k = 0; k < 7; ++k) {
                    ra = fmaf(xv[o + k], wra[k], ra);
                    rb = fmaf(xv[o + k], wrb[k], rb);
                }
                float va = fmaxf(fmaf(ra, s1a, f1a), 0.f);
                float vb = fmaxf(fmaf(rb, s1b, f1b), 0.f);
                *(unsigned*)&a1T[tt * 32 + 2 * cp] = pack_bf2(va, vb);
            }
        }
        __syncthreads();

        v4f acc[4][4];
        #pragma unroll
        for (int a = 0; a < 4; ++a)
            #pragma unroll
            for (int b = 0; b < 4; ++b)
                #pragma unroll
                for (int r = 0; r < 4; ++r) acc[a][b][r] = 0.f;

        #pragma unroll
        for (int k = 0; k < 7; ++k) {
            v8s af[4], bf[4];
            #pragma unroll
            for (int mt = 0; mt < 4; ++mt)
                af[mt] = *(const v8s*)&a1T[(wv * 64 + mt * 16 + m + k) * 32 + kg * 8];
            #pragma unroll
            for (int nt = 0; nt < 4; ++nt)
                bf[nt] = *(const v8s*)&ws2[(k * 64 + nt * 16 + m) * 32 + kg * 8];
            #pragma unroll
            for (int mt = 0; mt < 4; ++mt)
                #pragma unroll
                for (int nt = 0; nt < 4; ++nt)
                    acc[mt][nt] = __builtin_amdgcn_mfma_f32_16x16x32_bf16(af[mt], bf[nt], acc[mt][nt], 0, 0, 0);
        }

        // epilogue on RAW acc (bias folded at partial write): stats + pool store
        if (tc < 3) {
            #pragma unroll
            for (int nt = 0; nt < 4; ++nt) {
                const int c2 = nt * 16 + m;
                #pragma unroll
                for (int mt = 0; mt < 4; ++mt) {
                    const int tb = t0 + wv * 64 + mt * 16 + kg * 4;
                    float praw = (acc[mt][nt][0] + acc[mt][nt][1]) + (acc[mt][nt][2] + acc[mt][nt][3]);
                    scr[nt] += praw;
                    qcr[nt] = fmaf(acc[mt][nt][0], acc[mt][nt][0], qcr[nt]);
                    qcr[nt] = fmaf(acc[mt][nt][1], acc[mt][nt][1], qcr[nt]);
                    qcr[nt] = fmaf(acc[mt][nt][2], acc[mt][nt][2], qcr[nt]);
                    qcr[nt] = fmaf(acc[mt][nt][3], acc[mt][nt][3], qcr[nt]);
                    y2T[(n * 248 + (tb >> 2)) * 64 + c2] = f2bf(fmaf(praw, 0.25f, bias[nt]));
                }
            }
        } else {
            #pragma unroll
            for (int nt = 0; nt < 4; ++nt) {
                const int c2 = nt * 16 + m;
                #pragma unroll
                for (int mt = 0; mt < 4; ++mt) {
                    const int tb = t0 + wv * 64 + mt * 16 + kg * 4;
                    float praw = 0.f;
                    #pragma unroll
                    for (int r = 0; r < 4; ++r) {
                        float v = acc[mt][nt][r];
                        praw += v;
                        if (tb + r < 994) { scr[nt] += v; qcr[nt] = fmaf(v, v, qcr[nt]); }
                    }
                    if (tb < 992)
                        y2T[(n * 248 + (tb >> 2)) * 64 + c2] = f2bf(fmaf(praw, 0.25f, bias[nt]));
                }
            }
        }
    }
    #pragma unroll
    for (int nt = 0; nt < 4; ++nt) {
        float sc = scr[nt], qc = qcr[nt];
        sc += __shfl_xor(sc, 16, 64); qc += __shfl_xor(qc, 16, 64);
        sc += __shfl_xor(sc, 32, 64); qc += __shfl_xor(qc, 32, 64);
        if (kg == 0) { atomicAdd(&st[nt * 16 + m], sc); atomicAdd(&sq[nt * 16 + m], qc); }
    }
    __syncthreads();
    if (tid < 64) {
        // fold bias into stats: sum_t(v+b) = S + 994 b ; sum_t(v+b)^2 = Q + 2bS + 994 b^2
        const float bb = b2[tid];
        const float S = st[tid], Q = sq[tid];
        part2[n * 128 + tid] = S + 994.f * bb;
        part2[n * 128 + 64 + tid] = fmaf(2.f * bb, S, Q) + 994.f * bb * bb;
    }
}

// ---------------------------------------------------------------- conv3 MFMA: ONE block per n, a2T staged once, 4 weight segments
__global__ __launch_bounds__(256, 2) void k_conv3(
    const unsigned short* __restrict__ y2T, const float* __restrict__ scale2, const float* __restrict__ shift2,
    const unsigned short* __restrict__ w3bf, const float* __restrict__ b3,
    unsigned short* __restrict__ y3b, float* __restrict__ part3)
{
    __shared__ __align__(16) unsigned short a2T[262 * 72];
    __shared__ __align__(16) unsigned short ws3[7 * 64 * 32];
    __shared__ float s2s[64], f2s[64];
    __shared__ float st[128], sq[128];
    const int n = blockIdx.x;
    const int tid = threadIdx.x;
    if (tid < 64) { s2s[tid] = scale2[tid]; f2s[tid] = shift2[tid]; }
    if (tid < 128) { st[tid] = 0.f; sq[tid] = 0.f; }
    __syncthreads();

    // stage a2T[tt][c1] = bf16(relu(bn2(y2T[n][tt][c1]))), rows >= 248 zeroed (once per n)
    #pragma unroll
    for (int i = 0; i < 17; ++i) {
        int idx = i * 256 + tid;            // [0,4192) = 262*16
        if (idx < 4192) {
            int tt = idx >> 4, gq = idx & 15;
            uint2 o = make_uint2(0u, 0u);
            if (tt < 248) {
                ushort4 u = *(const ushort4*)&y2T[(n * 248 + tt) * 64 + gq * 4];
                float v0 = fmaxf(fmaf(bf2f(u.x), s2s[gq * 4 + 0], f2s[gq * 4 + 0]), 0.f);
                float v1 = fmaxf(fmaf(bf2f(u.y), s2s[gq * 4 + 1], f2s[gq * 4 + 1]), 0.f);
                float v2 = fmaxf(fmaf(bf2f(u.z), s2s[gq * 4 + 2], f2s[gq * 4 + 2]), 0.f);
                float v3 = fmaxf(fmaf(bf2f(u.w), s2s[gq * 4 + 3], f2s[gq * 4 + 3]), 0.f);
                o.x = pack_bf2(v0, v1);
                o.y = pack_bf2(v2, v3);
            }
            *(uint2*)&a2T[tt * 72 + gq * 4] = o;
        }
    }

    const int lane = tid & 63, wv = tid >> 6;
    const int m = lane & 15, kg = lane >> 4;
    // per-thread ws3 staging decomposition (7 v8s per segment)
    v8s wreg[7];
    int kidx[7], dsoff[7];
    #pragma unroll
    for (int i = 0; i < 7; ++i) {
        int idx = i * 256 + tid;
        int k = idx >> 8, rest = idx & 255;
        int c2l = rest >> 2, h = rest & 3;
        kidx[i] = (k * 128 + c2l) * 32 + h * 8;          // src offset within [ch][*]: ch stride = 7*128*32
        dsoff[i] = (k * 64 + c2l) * 32 + h * 8;
    }
    // prefetch segment 0 (c2h=0, ch=0)
    #pragma unroll
    for (int i = 0; i < 7; ++i) wreg[i] = *(const v8s*)&w3bf[kidx[i]];

    v4f acc[4][4];
    for (int seg = 0; seg < 4; ++seg) {
        const int c2h = seg >> 1, ch = seg & 1;
        __syncthreads();   // a2T staged (seg 0) / prev ws3 reads done
        #pragma unroll
        for (int i = 0; i < 7; ++i) *(v8s*)&ws3[dsoff[i]] = wreg[i];
        if (seg < 3) {
            const int nc2h = (seg + 1) >> 1, nch = (seg + 1) & 1;
            const long base = (long)nch * (7 * 128 * 32) + nc2h * (64 * 32);
            #pragma unroll
            for (int i = 0; i < 7; ++i) wreg[i] = *(const v8s*)&w3bf[base + kidx[i]];
        }
        __syncthreads();
        if (ch == 0) {
            #pragma unroll
            for (int a = 0; a < 4; ++a)
                #pragma unroll
                for (int b = 0; b < 4; ++b)
                    #pragma unroll
                    for (int r = 0; r < 4; ++r) acc[a][b][r] = 0.f;
        }
        #pragma unroll
        for (int k = 0; k < 7; ++k) {
            v8s af[4], bf[4];
            #pragma unroll
            for (int mt = 0; mt < 4; ++mt)
                af[mt] = *(const v8s*)&a2T[(wv * 64 + mt * 16 + m + k) * 72 + ch * 32 + kg * 8];
            #pragma unroll
            for (int nt = 0; nt < 4; ++nt)
                bf[nt] = *(const v8s*)&ws3[(k * 64 + nt * 16 + m) * 32 + kg * 8];
            #pragma unroll
            for (int mt = 0; mt < 4; ++mt)
                #pragma unroll
                for (int nt = 0; nt < 4; ++nt)
                    acc[mt][nt] = __builtin_amdgcn_mfma_f32_16x16x32_bf16(af[mt], bf[nt], acc[mt][nt], 0, 0, 0);
        }
        if (ch == 1) {
            // epilogue for this c2h on RAW acc (bias folded at partial write)
            #pragma unroll
            for (int nt = 0; nt < 4; ++nt) {
                const int c2l = nt * 16 + m;
                const int c2 = c2h * 64 + c2l;
                const float bb = b3[c2];
                float scr = 0.f, qcr = 0.f;
                #pragma unroll
                for (int mt = 0; mt < 4; ++mt) {
                    const int ts = wv * 64 + mt * 16 + kg * 4;
                    if (!(mt == 3 && wv == 3)) {
                        float praw = (acc[mt][nt][0] + acc[mt][nt][1]) + (acc[mt][nt][2] + acc[mt][nt][3]);
                        scr += praw;
                        qcr = fmaf(acc[mt][nt][0], acc[mt][nt][0], qcr);
                        qcr = fmaf(acc[mt][nt][1], acc[mt][nt][1], qcr);
                        qcr = fmaf(acc[mt][nt][2], acc[mt][nt][2], qcr);
                        qcr = fmaf(acc[mt][nt][3], acc[mt][nt][3], qcr);
                        y3b[(n * 128 + c2) * 60 + (ts >> 2)] = f2bf(fmaf(praw, 0.25f, bb));
                    } else {
                        #pragma unroll
                        for (int r = 0; r < 4; ++r) {
                            float v = acc[mt][nt][r];
                            if (ts + r < 242) { scr += v; qcr = fmaf(v, v, qcr); }
                        }
                    }
                }
                scr += __shfl_xor(scr, 16, 64); qcr += __shfl_xor(qcr, 16, 64);
                scr += __shfl_xor(scr, 32, 64); qcr += __shfl_xor(qcr, 32, 64);
                if (kg == 0) { atomicAdd(&st[c2], scr); atomicAdd(&sq[c2], qcr); }
            }
        }
    }
    __syncthreads();
    if (tid < 128) {
        const float bb = b3[tid];
        const float S = st[tid], Q = sq[tid];
        part3[(long)n * 256 + tid] = S + 242.f * bb;
        part3[(long)n * 256 + 128 + tid] = fmaf(2.f * bb, S, Q) + 242.f * bb * bb;
    }
}

// ---------------------------------------------------------------- h0 = bf16(relu(bn3(y3b)) + pe), ushort4 vectorized (4 | 60 -> c uniform per quad)
__global__ __launch_bounds__(256) void k_h0(
    const unsigned short* __restrict__ y3b, const float* __restrict__ scale3, const float* __restrict__ shift3,
    const float* __restrict__ pe, unsigned short* __restrict__ h0b)
{
    const int n = blockIdx.y;
    const int idx = blockIdx.x * 256 + threadIdx.x;   // quad index < 1920
    if (idx < 1920) {
        const int c = idx / 15;
        const float sc = scale3[c], sh = shift3[c], pv = pe[n * 128 + c];
        ushort4 u = *(const ushort4*)&y3b[n * FLATD + idx * 4];
        ushort4 o;
        o.x = f2bf(fmaxf(fmaf(bf2f(u.x), sc, sh), 0.f) + pv);
        o.y = f2bf(fmaxf(fmaf(bf2f(u.y), sc, sh), 0.f) + pv);
        o.z = f2bf(fmaxf(fmaf(bf2f(u.z), sc, sh), 0.f) + pv);
        o.w = f2bf(fmaxf(fmaf(bf2f(u.w), sc, sh), 0.f) + pv);
        *(ushort4*)&h0b[n * FLATD + idx * 4] = o;
    }
}

// ---------------------------------------------------------------- bf16 MFMA GEMM: plain stores into per-slice buffers
__global__ __launch_bounds__(256) void k_gemm_mfma(
    const unsigned short* __restrict__ A, const unsigned short* __restrict__ BT,
    float* __restrict__ C, int K, int Kslice)
{
    __shared__ __align__(16) unsigned short As[128 * 40];
    __shared__ __align__(16) unsigned short Bs[128 * 40];
    const int tid = threadIdx.x;
    const int m0 = blockIdx.x * 128, n0 = blockIdx.y * 128;
    const int k0 = blockIdx.z * Kslice, kend = k0 + Kslice;
    float* Cd = C + (long)blockIdx.z * (NN * EMBD);
    const int lane = tid & 63, wvv = tid >> 6;
    const int wm = (wvv & 1) * 64, wn = (wvv >> 1) * 64;
    const int m = lane & 15, kg = lane >> 4;
    const int sr = tid >> 1, sh = (tid & 1) * 16;
    v4f acc[4][4];
    #pragma unroll
    for (int a = 0; a < 4; ++a)
        #pragma unroll
        for (int b = 0; b < 4; ++b)
            #pragma unroll
            for (int r = 0; r < 4; ++r) acc[a][b][r] = 0.f;

    for (int kt = k0; kt < kend; kt += 32) {
        const unsigned short* ap = &A[(long)(m0 + sr) * K + kt + sh];
        v8s a0 = *(const v8s*)ap;
        v8s a1 = *(const v8s*)(ap + 8);
        const unsigned short* bp = &BT[(long)(n0 + sr) * K + kt + sh];
        v8s b0 = *(const v8s*)bp;
        v8s b1 = *(const v8s*)(bp + 8);
        __syncthreads();
        *(v8s*)&As[sr * 40 + sh] = a0;
        *(v8s*)&As[sr * 40 + sh + 8] = a1;
        *(v8s*)&Bs[sr * 40 + sh] = b0;
        *(v8s*)&Bs[sr * 40 + sh + 8] = b1;
        __syncthreads();
        v8s af[4], bf[4];
        #pragma unroll
        for (int mt = 0; mt < 4; ++mt) af[mt] = *(const v8s*)&As[(wm + mt * 16 + m) * 40 + kg * 8];
        #pragma unroll
        for (int nt = 0; nt < 4; ++nt) bf[nt] = *(const v8s*)&Bs[(wn + nt * 16 + m) * 40 + kg * 8];
        #pragma unroll
        for (int mt = 0; mt < 4; ++mt)
            #pragma unroll
            for (int nt = 0; nt < 4; ++nt)
                acc[mt][nt] = __builtin_amdgcn_mfma_f32_16x16x32_bf16(af[mt], bf[nt], acc[mt][nt], 0, 0, 0);
    }
    #pragma unroll
    for (int mt = 0; mt < 4; ++mt) {
        const int row = m0 + wm + mt * 16 + kg * 4;
        #pragma unroll
        for (int nt = 0; nt < 4; ++nt) {
            const int col = n0 + wn + nt * 16 + m;
            #pragma unroll
            for (int r = 0; r < 4; ++r)
                Cd[(long)(row + r) * EMBD + col] = acc[mt][nt][r];
        }
    }
}

// ---------------------------------------------------------------- combine split-K partials
__global__ __launch_bounds__(256) void k_combine(float* __restrict__ P, int nsl)
{
    long i = (long)(blockIdx.x * 256 + threadIdx.x) * 4;
    float4 a = *(float4*)&P[i];
    for (int s = 1; s < nsl; ++s) {
        float4 c = *(const float4*)&P[(long)s * 1572864 + i];
        a.x += c.x; a.y += c.y; a.z += c.z; a.w += c.w;
    }
    *(float4*)&P[i] = a;
}

// ---------------------------------------------------------------- fused CSR gather + gcn finalize (bf16 out)
__global__ __launch_bounds__(256) void k_gcn_gather(
    const float* __restrict__ P, const int* __restrict__ rowptr,
    const int* __restrict__ csr_src, const float* __restrict__ csr_coef,
    const float* __restrict__ invd, const float* __restrict__ b,
    unsigned short* __restrict__ Hb)
{
    const int n = blockIdx.x, tid = threadIdx.x;
    const int beg = rowptr[n], end = rowptr[n + 1];
    float a0 = 0.f, a1 = 0.f, a2 = 0.f;
    for (int j = beg; j < end; ++j) {
        const int s = csr_src[j];
        const float cf = csr_coef[j];
        const float* Pr = P + (long)s * EMBD;
        a0 = fmaf(cf, Pr[tid], a0);
        a1 = fmaf(cf, Pr[tid + 256], a1);
        a2 = fmaf(cf, Pr[tid + 512], a2);
    }
    const float inv = invd[n];
    const float* Pn = P + (long)n * EMBD;
    float v0 = fmaxf(fmaf(Pn[tid], inv, a0) + b[tid], 0.f);
    float v1 = fmaxf(fmaf(Pn[tid + 256], inv, a1) + b[tid + 256], 0.f);
    float v2 = fmaxf(fmaf(Pn[tid + 512], inv, a2) + b[tid + 512], 0.f);
    Hb[(long)n * EMBD + tid] = f2bf(v0);
    Hb[(long)n * EMBD + tid + 256] = f2bf(v1);
    Hb[(long)n * EMBD + tid + 512] = f2bf(v2);
}

// ---------------------------------------------------------------- pool + dense + log_softmax (bf16 input)
__global__ __launch_bounds__(256) void k_head(
    const unsigned short* __restrict__ Hb, const float* __restrict__ dw, const float* __restrict__ db,
    float* __restrict__ out)
{
    __shared__ float ls[4];
    const int b = blockIdx.x, tid = threadIdx.x;
    if (tid < 4) ls[tid] = 0.f;
    __syncthreads();
    float pl0 = 0.f, pl1 = 0.f, pl2 = 0.f, pl3 = 0.f;
    for (int fo = 0; fo < 3; ++fo) {
        const int f = tid + 256 * fo;
        float s = 0.f;
        for (int r = 0; r < 64; ++r) s += bf2f(Hb[(b * 64 + r) * EMBD + f]);
        s *= (1.f / 64.f);
        pl0 = fmaf(s, dw[f * 4 + 0], pl0);
        pl1 = fmaf(s, dw[f * 4 + 1], pl1);
        pl2 = fmaf(s, dw[f * 4 + 2], pl2);
        pl3 = fmaf(s, dw[f * 4 + 3], pl3);
    }
    #pragma unroll
    for (int off = 32; off > 0; off >>= 1) {
        pl0 += __shfl_down(pl0, off, 64);
        pl1 += __shfl_down(pl1, off, 64);
        pl2 += __shfl_down(pl2, off, 64);
        pl3 += __shfl_down(pl3, off, 64);
    }
    if ((tid & 63) == 0) {
        atomicAdd(&ls[0], pl0); atomicAdd(&ls[1], pl1);
        atomicAdd(&ls[2], pl2); atomicAdd(&ls[3], pl3);
    }
    __syncthreads();
    if (tid == 0) {
        float l0 = ls[0] + db[0], l1 = ls[1] + db[1], l2 = ls[2] + db[2], l3 = ls[3] + db[3];
        float m = fmaxf(fmaxf(l0, l1), fmaxf(l2, l3));
        float sum = expf(l0 - m) + expf(l1 - m) + expf(l2 - m) + expf(l3 - m);
        float lse = logf(sum);
        out[b * 4 + 0] = l0 - m - lse;
        out[b * 4 + 1] = l1 - m - lse;
        out[b * 4 + 2] = l2 - m - lse;
        out[b * 4 + 3] = l3 - m - lse;
    }
}

// ================================================================ launch
extern "C" void kernel_launch(void* const* d_in, const int* in_sizes, int n_in,
                              void* d_out, int out_size, void* d_ws, size_t ws_size,
                              hipStream_t stream)
{
    (void)in_sizes; (void)n_in; (void)out_size; (void)ws_size;
    const float* x   = (const float*)d_in[0];
    const float* pos = (const float*)d_in[1];
    const int*   ei  = (const int*)d_in[2];
    const float* w1  = (const float*)d_in[4];
    const float* b1  = (const float*)d_in[5];
    const float* g1  = (const float*)d_in[6];
    const float* bt1 = (const float*)d_in[7];
    const float* w2  = (const float*)d_in[8];
    const float* b2  = (const float*)d_in[9];
    const float* g2  = (const float*)d_in[10];
    const float* bt2 = (const float*)d_in[11];
    const float* w3  = (const float*)d_in[12];
    const float* b3  = (const float*)d_in[13];
    const float* g3  = (const float*)d_in[14];
    const float* bt3 = (const float*)d_in[15];
    const float* pw1 = (const float*)d_in[16];
    const float* pb1 = (const float*)d_in[17];
    const float* pw2 = (const float*)d_in[18];
    const float* pb2 = (const float*)d_in[19];
    const float* gw1 = (const float*)d_in[20];
    const float* gb1 = (const float*)d_in[21];
    const float* gw2 = (const float*)d_in[22];
    const float* gb2 = (const float*)d_in[23];
    const float* dw  = (const float*)d_in[24];
    const float* db  = (const float*)d_in[25];

    float* wsf = (float*)d_ws;
    // y2T bf16 occupies floats [0, 16252928) until conv3; then reused for GCN buffers.
    // pe MUST live outside [0, 16252928): k_prep writes it BEFORE conv2 overwrites y2T.
    unsigned short* y2T = (unsigned short*)wsf;
    float* P0  = wsf;                                           // 8 slices x 1,572,864 f
    unsigned short* X3b = (unsigned short*)(wsf + 12582912);    // 1,572,864 bf16
    unsigned short* y3b = (unsigned short*)(wsf + 16252928);    // 15,728,640 bf16 -> [16252928, 24117248)
    float* part1 = wsf + 24117248;                              // 35*512 = 17,920
    float* part2 = wsf + 24150016;                              // 262,144
    float* part3 = wsf + 24412160;                              // 524,288 -> end 24936448
    unsigned short* h0b = (unsigned short*)(wsf + 24936448);    // 15,728,640 bf16 -> [24936448, 32800768)
    unsigned short* gw1T = (unsigned short*)(wsf + 32800768);   // 5,898,240 bf16
    unsigned short* gw2T = (unsigned short*)(wsf + 35749888);   // 589,824 bf16
    unsigned short* w2bf = (unsigned short*)(wsf + 36044800);   // 14,336 bf16
    unsigned short* w3bf = (unsigned short*)(wsf + 36051968);   // 57,344 bf16
    float* fb = wsf + 36081536;                                 // 448 f
    float* scale1 = fb,       *shift1 = fb + 32;
    float* scale2 = fb + 64,  *shift2 = fb + 128;
    float* scale3 = fb + 192, *shift3 = fb + 320;
    float* dinv = wsf + 36081984;                               // 2048
    float* invd = wsf + 36084032;                               // 2048
    int* cnt    = (int*)(wsf + 36086080);                       // 2048
    int* cursor = (int*)(wsf + 36088128);                       // 2048 (contiguous with cnt)
    int* rowptr = (int*)(wsf + 36090176);                       // 2049
    int* csr_src = (int*)(wsf + 36092240);                      // 32768
    float* csr_coef = wsf + 36125008;                           // 32768 -> end 36157776
    float* pe  = wsf + 36157776;                                // 262,144 f (tail; survives conv2/conv3)

    // mega-prep: cvt w2/w3, transpose gw1/gw2, zero cnt+cursor, pos-MLP, x-moments
    k_prep<<<2648, 256, 0, stream>>>(w2, w2bf, w3, w3bf, gw1, gw1T, gw2, gw2T,
                                     cnt, pos, pw1, pb1, pw2, pb2, pe, x, part1);
    // aux: bn1 finalize (block 0) + CSR count (blocks 1..128)
    k_aux<<<129, 256, 0, stream>>>(part1, w1, b1, g1, bt1, scale1, shift1, ei, cnt);

    // conv pipeline (conv2 block 2048 = CSR scan; reduce2 blocks 64+ = CSR fill)
    k_conv2<<<2049, 256, 0, stream>>>(x, w1, b1, scale1, shift1, w2bf, b2, y2T, part2,
                                      cnt, rowptr, dinv, invd);
    k_reduce_stats<<<192, 256, 0, stream>>>(part2, g2, bt2, scale2, shift2,
                                            2048, 128, 64, 1.f / (2048.f * 994.f), 64,
                                            ei, rowptr, cursor, dinv, csr_src, csr_coef);
    k_conv3<<<2048, 256, 0, stream>>>(y2T, scale2, shift2, w3bf, b3, y3b, part3);
    k_reduce_stats<<<128, 256, 0, stream>>>(part3, g3, bt3, scale3, shift3,
                                            2048, 256, 128, 1.f / (2048.f * 242.f), 128,
                                            ei, rowptr, cursor, dinv, csr_src, csr_coef);
    k_h0<<<dim3(8, 2048), 256, 0, stream>>>(y3b, scale3, shift3, pe, h0b);

    // GCN layer 1: split-K=8 GEMM -> combine -> gather+fin (bf16)
    k_gemm_mfma<<<dim3(16, 6, 8), 256, 0, stream>>>(h0b, gw1T, P0, FLATD, FLATD / 8);
    k_combine<<<1536, 256, 0, stream>>>(P0, 8);
    k_gcn_gather<<<2048, 256, 0, stream>>>(P0, rowptr, csr_src, csr_coef, invd, gb1, X3b);

    // GCN layer 2: split-K=2 GEMM -> combine -> gather+fin
    k_gemm_mfma<<<dim3(16, 6, 2), 256, 0, stream>>>(X3b, gw2T, P0, EMBD, EMBD / 2);
    k_combine<<<1536, 256, 0, stream>>>(P0, 2);
    k_gcn_gather<<<2048, 256, 0, stream>>>(P0, rowptr, csr_src, csr_coef, invd, gb2, X3b);

    k_head<<<32, 256, 0, stream>>>(X3b, dw, db, (float*)d_out);
}